// Round 2
// baseline (410.271 us; speedup 1.0000x reference)
//
#include <hip/hip_runtime.h>
#include <hip/hip_bf16.h>
#include <cstdint>
#include <cstddef>

#define B 64
#define T 1024
#define DQ 1024
#define DV 512
#define A_DIM 512
#define F_DIM 32
#define KW 31
#define M_TOT (B*T)
#define KEXT 544      // DV + F_DIM
#define NCHUNK 17     // KEXT / 32

typedef __attribute__((ext_vector_type(8))) short short8;
typedef __attribute__((ext_vector_type(4))) float f32x4;

static __device__ __forceinline__ unsigned short f2bf(float f) {
    unsigned int u = __builtin_bit_cast(unsigned int, f);
    u += 0x7fffu + ((u >> 16) & 1u);   // RNE
    return (unsigned short)(u >> 16);
}

static __device__ __forceinline__ float tanh_fast(float x) {
    // tanh(x) = 1 - 2/(exp(2x)+1), exact identity; ~1e-6 rel err in fp32
    float e = __expf(2.0f * x);
    return 1.0f - 2.0f * __builtin_amdgcn_rcpf(e + 1.0f);
}

// ---------- prep: processed_query [B, A] fp32 ----------
__global__ void pq_kernel(const float* __restrict__ query, const float* __restrict__ Wq,
                          float* __restrict__ pq) {
    int idx = blockIdx.x * 256 + threadIdx.x;      // 64*512 = 32768
    int b = idx >> 9, a = idx & 511;
    const float* qr = query + (size_t)b * DQ;
    float acc = 0.f;
    #pragma unroll 4
    for (int k = 0; k < DQ; ++k) acc += qr[k] * Wq[(size_t)k * A_DIM + a];
    pq[idx] = acc;
}

// ---------- prep: B_ext^T  [A][KEXT] bf16  (W_inputs stacked with W_loc, transposed) ----------
__global__ void bt_kernel(const float* __restrict__ Wi, const float* __restrict__ Wl,
                          unsigned short* __restrict__ Bt) {
    int a = blockIdx.x;   // 512 blocks
    for (int k = threadIdx.x; k < KEXT; k += 256) {
        float v = (k < DV) ? Wi[(size_t)k * A_DIM + a] : Wl[(size_t)(k - DV) * A_DIM + a];
        Bt[(size_t)a * KEXT + k] = f2bf(v);
    }
}

// ---------- prep: location conv  [M][F] bf16 ----------
__global__ void conv_kernel(const float* __restrict__ old_, const float* __restrict__ cum_,
                            const float* __restrict__ lk, unsigned short* __restrict__ convb) {
    __shared__ float sOld[158], sCum[158];
    __shared__ float sLK[KW * 2 * F_DIM];
    int b = blockIdx.x >> 3, t0 = (blockIdx.x & 7) * 128;
    int tid = threadIdx.x;   // 128 threads
    for (int j = tid; j < 158; j += 128) {
        int tt = t0 - 15 + j;
        bool ok = (tt >= 0 && tt < T);
        sOld[j] = ok ? old_[b * T + tt] : 0.f;
        sCum[j] = ok ? cum_[b * T + tt] : 0.f;
    }
    for (int j = tid; j < KW * 2 * F_DIM; j += 128) sLK[j] = lk[j];
    __syncthreads();
    float acc[F_DIM];
    #pragma unroll
    for (int f = 0; f < F_DIM; ++f) acc[f] = 0.f;
    for (int k = 0; k < KW; ++k) {
        float o = sOld[tid + k], c = sCum[tid + k];
        const float* lo = &sLK[(k * 2 + 0) * F_DIM];
        const float* lc = &sLK[(k * 2 + 1) * F_DIM];
        #pragma unroll
        for (int f = 0; f < F_DIM; ++f) acc[f] += o * lo[f] + c * lc[f];
    }
    unsigned short* dst = convb + (size_t)(b * T + t0 + tid) * F_DIM;
    #pragma unroll
    for (int f = 0; f < F_DIM; ++f) dst[f] = f2bf(acc[f]);
}

// ---------- fused GEMM (M=65536, K=544, N=512) + tanh + dot(v_w) -> score[M] ----------
__launch_bounds__(256, 2)
__global__ void gemm_score(const float* __restrict__ values,
                           const unsigned short* __restrict__ Bt,
                           const unsigned short* __restrict__ convb,
                           const float* __restrict__ pq,
                           const float* __restrict__ vw,
                           float* __restrict__ score) {
    __shared__ __align__(16) short sA[64 * 40];    // 64 rows x 32 k, pad to 40
    __shared__ __align__(16) short sB[512 * 40];   // 512 a-rows x 32 k, pad to 40
    __shared__ float sPQ[512];
    __shared__ float sVW[512];
    __shared__ float sSc[64];                      // cross-wave score partials
    int tid = threadIdx.x;
    int m0 = blockIdx.x * 64;
    int b = m0 >> 10;
    for (int j = tid; j < 512; j += 256) { sPQ[j] = pq[b * 512 + j]; sVW[j] = vw[j]; }
    int w = tid >> 6, lane = tid & 63, q = lane >> 4, l15 = lane & 15;
    int wm = w & 1, wn = w >> 1;      // wave: rows wm*32..+31, cols wn*256..+255
    f32x4 acc0[16], acc1[16];
    #pragma unroll
    for (int n = 0; n < 16; ++n) { acc0[n] = (f32x4)0.f; acc1[n] = (f32x4)0.f; }
    int arow = tid >> 2, aseg = tid & 3;
    for (int c = 0; c < NCHUNK; ++c) {
        __syncthreads();
        // stage A-tile: 64 rows x 32 k bf16
        if (c < 16) {
            const float* src = values + (size_t)(m0 + arow) * DV + c * 32 + aseg * 8;
            float4 x0 = *(const float4*)src;
            float4 x1 = *(const float4*)(src + 4);
            short8 pk;
            pk[0] = (short)f2bf(x0.x); pk[1] = (short)f2bf(x0.y);
            pk[2] = (short)f2bf(x0.z); pk[3] = (short)f2bf(x0.w);
            pk[4] = (short)f2bf(x1.x); pk[5] = (short)f2bf(x1.y);
            pk[6] = (short)f2bf(x1.z); pk[7] = (short)f2bf(x1.w);
            *(short8*)&sA[arow * 40 + aseg * 8] = pk;
        } else {
            short8 pk = *(const short8*)(const void*)(convb + (size_t)(m0 + arow) * F_DIM + aseg * 8);
            *(short8*)&sA[arow * 40 + aseg * 8] = pk;
        }
        // stage B-tile: 512 a-rows x 32 k bf16 (shared by all 4 waves)
        #pragma unroll
        for (int j = 0; j < 8; ++j) {
            int task = j * 256 + tid;
            int a = task >> 2, seg = task & 3;
            short8 pk = *(const short8*)(const void*)(Bt + (size_t)a * KEXT + c * 32 + seg * 8);
            *(short8*)&sB[a * 40 + seg * 8] = pk;
        }
        __syncthreads();
        short8 af0 = *(const short8*)&sA[(wm * 32 + l15) * 40 + q * 8];
        short8 af1 = *(const short8*)&sA[(wm * 32 + 16 + l15) * 40 + q * 8];
        #pragma unroll
        for (int n = 0; n < 16; ++n) {
            short8 bfr = *(const short8*)&sB[(wn * 256 + n * 16 + l15) * 40 + q * 8];
            acc0[n] = __builtin_amdgcn_mfma_f32_16x16x32_bf16(af0, bfr, acc0[n], 0, 0, 0);
            acc1[n] = __builtin_amdgcn_mfma_f32_16x16x32_bf16(af1, bfr, acc1[n], 0, 0, 0);
        }
    }
    // epilogue: score[m] = sum_a tanh(PV+PQ)·v_w  (v_b dropped: softmax shift-invariant)
    // Each wave covers half the N-columns -> cross-wave add via LDS.
    float prt[2][4];
    #pragma unroll
    for (int mb = 0; mb < 2; ++mb) {
        #pragma unroll
        for (int r = 0; r < 4; ++r) {
            float s = 0.f;
            #pragma unroll
            for (int n = 0; n < 16; ++n) {
                int col = wn * 256 + n * 16 + l15;
                float x = (mb ? acc1[n][r] : acc0[n][r]) + sPQ[col];
                s += tanh_fast(x) * sVW[col];
            }
            #pragma unroll
            for (int off = 1; off < 16; off <<= 1) s += __shfl_xor(s, off, 64);
            prt[mb][r] = s;
        }
    }
    if (wn == 0 && l15 == 0) {
        #pragma unroll
        for (int mb = 0; mb < 2; ++mb)
            #pragma unroll
            for (int r = 0; r < 4; ++r)
                sSc[wm * 32 + mb * 16 + q * 4 + r] = prt[mb][r];
    }
    __syncthreads();
    if (wn == 1 && l15 == 0) {
        #pragma unroll
        for (int mb = 0; mb < 2; ++mb)
            #pragma unroll
            for (int r = 0; r < 4; ++r) {
                int row = wm * 32 + mb * 16 + q * 4 + r;
                score[m0 + row] = sSc[row] + prt[mb][r];
            }
    }
}

// ---------- softmax + forward-attention recursion + state outputs ----------
__global__ void softmax_fwd(const float* __restrict__ score,
                            const float* __restrict__ alpha,
                            const float* __restrict__ cum,
                            float* __restrict__ out) {
    int b = blockIdx.x, t = threadIdx.x;   // 1024 threads
    __shared__ float sred[16];
    __shared__ float sbc;
    float sc = score[b * T + t];
    int wid = t >> 6, lane = t & 63;
    float m = sc;
    #pragma unroll
    for (int off = 32; off; off >>= 1) m = fmaxf(m, __shfl_xor(m, off, 64));
    if (lane == 0) sred[wid] = m;
    __syncthreads();
    if (t == 0) { float mm = sred[0]; for (int i = 1; i < 16; ++i) mm = fmaxf(mm, sred[i]); sbc = mm; }
    __syncthreads();
    float M = sbc;
    float e = __expf(sc - M);
    float s = e;
    #pragma unroll
    for (int off = 32; off; off >>= 1) s += __shfl_xor(s, off, 64);
    __syncthreads();
    if (lane == 0) sred[wid] = s;
    __syncthreads();
    if (t == 0) { float ss = 0.f; for (int i = 0; i < 16; ++i) ss += sred[i]; sbc = ss; }
    __syncthreads();
    float sn = e / sbc;
    float a_t = alpha[b * T + t];
    float a_p = (t > 0) ? alpha[b * T + t - 1] : 0.f;
    float ua = (0.5f * (a_t + a_p) + 1e-8f) * sn;
    float u = ua;
    #pragma unroll
    for (int off = 32; off; off >>= 1) u += __shfl_xor(u, off, 64);
    __syncthreads();
    if (lane == 0) sred[wid] = u;
    __syncthreads();
    if (t == 0) { float ss = 0.f; for (int i = 0; i < 16; ++i) ss += sred[i]; sbc = ss; }
    __syncthreads();
    float wgt = ua / sbc;
    float* attnw  = out + B * DV;
    float* ncum   = attnw + B * T;
    float* nold   = ncum + B * T;
    float* nalpha = nold + B * T;
    attnw[b * T + t]  = wgt;
    ncum[b * T + t]   = cum[b * T + t] + sn;
    nold[b * T + t]   = wgt;
    nalpha[b * T + t] = wgt;
    if (t < DV) out[b * DV + t] = 0.f;   // zero context region for atomics
}

// ---------- context = attn_weights @ values ----------
__global__ void context_kernel(const float* __restrict__ values, float* __restrict__ out) {
    const float* attnw = out + B * DV;
    int bid = blockIdx.x;                 // 1024 = 64 b x 2 d-half x 8 t-slice
    int b = bid >> 4, r = bid & 15, dh = r & 1, sl = r >> 1;
    int d = dh * 256 + threadIdx.x;
    float acc = 0.f;
    int tbase = sl * 128;
    #pragma unroll 4
    for (int tt = 0; tt < 128; ++tt) {
        int t = tbase + tt;
        acc += attnw[b * T + t] * values[(size_t)(b * T + t) * DV + d];
    }
    atomicAdd(&out[b * DV + d], acc);
}

extern "C" void kernel_launch(void* const* d_in, const int* in_sizes, int n_in,
                              void* d_out, int out_size, void* d_ws, size_t ws_size,
                              hipStream_t stream) {
    const float* query  = (const float*)d_in[0];
    const float* values = (const float*)d_in[1];
    const float* cum    = (const float*)d_in[2];
    const float* old_   = (const float*)d_in[3];
    const float* alpha  = (const float*)d_in[4];
    const float* Wq     = (const float*)d_in[5];
    const float* Wi     = (const float*)d_in[6];
    const float* vw     = (const float*)d_in[7];
    // d_in[8] = v_b : dropped (softmax shift-invariant)
    const float* lk     = (const float*)d_in[9];
    const float* Wl     = (const float*)d_in[10];
    float* out = (float*)d_out;
    char* ws = (char*)d_ws;
    float* ws_pq            = (float*)(ws);                    // 131072 B
    float* ws_score         = (float*)(ws + 131072);           // 262144 B
    unsigned short* ws_Bt   = (unsigned short*)(ws + 393216);  // 557056 B
    unsigned short* ws_conv = (unsigned short*)(ws + 1048576); // 4 MiB

    pq_kernel<<<128, 256, 0, stream>>>(query, Wq, ws_pq);
    bt_kernel<<<512, 256, 0, stream>>>(Wi, Wl, ws_Bt);
    conv_kernel<<<512, 128, 0, stream>>>(old_, cum, lk, ws_conv);
    gemm_score<<<1024, 256, 0, stream>>>(values, ws_Bt, ws_conv, ws_pq, vw, ws_score);
    softmax_fwd<<<64, 1024, 0, stream>>>(ws_score, alpha, cum, out);
    context_kernel<<<1024, 256, 0, stream>>>(values, out);
}

// Round 3
// 314.852 us; speedup vs baseline: 1.3031x; 1.3031x over previous
//
#include <hip/hip_runtime.h>
#include <hip/hip_bf16.h>
#include <cstdint>
#include <cstddef>

#define B 64
#define T 1024
#define DQ 1024
#define DV 512
#define A_DIM 512
#define F_DIM 32
#define KW 31
#define M_TOT (B*T)
#define KEXT 544      // DV + F_DIM
#define NCHUNK 17     // KEXT / 32

typedef __attribute__((ext_vector_type(8))) short short8;
typedef __attribute__((ext_vector_type(4))) float f32x4;

static __device__ __forceinline__ unsigned short f2bf(float f) {
    unsigned int u = __builtin_bit_cast(unsigned int, f);
    u += 0x7fffu + ((u >> 16) & 1u);   // RNE
    return (unsigned short)(u >> 16);
}

static __device__ __forceinline__ float tanh_fast(float x) {
    // tanh(x) = 1 - 2/(exp(2x)+1), exact identity; ~1e-6 rel err in fp32
    float e = __expf(2.0f * x);
    return 1.0f - 2.0f * __builtin_amdgcn_rcpf(e + 1.0f);
}

// ---------- prep: processed_query [B, A] fp32 ----------
// grid 512 = 64 b x 8 a-chunks(64); 256 thr = 64 a_local x 4 k-slices(256)
__global__ void pq_kernel(const float* __restrict__ query, const float* __restrict__ Wq,
                          float* __restrict__ pq) {
    __shared__ float red[4][64];
    int b = blockIdx.x >> 3, a0 = (blockIdx.x & 7) * 64;
    int al = threadIdx.x & 63, ks = threadIdx.x >> 6;
    const float* qr = query + (size_t)b * DQ + ks * 256;
    const float* wc = Wq + (size_t)(ks * 256) * A_DIM + a0 + al;
    float acc = 0.f;
    #pragma unroll 8
    for (int k = 0; k < 256; ++k) acc += qr[k] * wc[(size_t)k * A_DIM];
    red[ks][al] = acc;
    __syncthreads();
    if (ks == 0) {
        float s = red[0][al] + red[1][al] + red[2][al] + red[3][al];
        pq[b * A_DIM + a0 + al] = s;
    }
}

// ---------- prep: B_ext^T  [A][KEXT] bf16  (W_inputs stacked with W_loc, transposed) ----------
__global__ void bt_kernel(const float* __restrict__ Wi, const float* __restrict__ Wl,
                          unsigned short* __restrict__ Bt) {
    int a = blockIdx.x;   // 512 blocks
    for (int k = threadIdx.x; k < KEXT; k += 256) {
        float v = (k < DV) ? Wi[(size_t)k * A_DIM + a] : Wl[(size_t)(k - DV) * A_DIM + a];
        Bt[(size_t)a * KEXT + k] = f2bf(v);
    }
}

// ---------- prep: location conv  [M][F] bf16 ----------
__global__ void conv_kernel(const float* __restrict__ old_, const float* __restrict__ cum_,
                            const float* __restrict__ lk, unsigned short* __restrict__ convb) {
    __shared__ float sOld[158], sCum[158];
    __shared__ float sLK[KW * 2 * F_DIM];
    int b = blockIdx.x >> 3, t0 = (blockIdx.x & 7) * 128;
    int tid = threadIdx.x;   // 128 threads
    for (int j = tid; j < 158; j += 128) {
        int tt = t0 - 15 + j;
        bool ok = (tt >= 0 && tt < T);
        sOld[j] = ok ? old_[b * T + tt] : 0.f;
        sCum[j] = ok ? cum_[b * T + tt] : 0.f;
    }
    for (int j = tid; j < KW * 2 * F_DIM; j += 128) sLK[j] = lk[j];
    __syncthreads();
    float acc[F_DIM];
    #pragma unroll
    for (int f = 0; f < F_DIM; ++f) acc[f] = 0.f;
    for (int k = 0; k < KW; ++k) {
        float o = sOld[tid + k], c = sCum[tid + k];
        const float* lo = &sLK[(k * 2 + 0) * F_DIM];
        const float* lc = &sLK[(k * 2 + 1) * F_DIM];
        #pragma unroll
        for (int f = 0; f < F_DIM; ++f) acc[f] += o * lo[f] + c * lc[f];
    }
    unsigned short* dst = convb + (size_t)(b * T + t0 + tid) * F_DIM;
    #pragma unroll
    for (int f = 0; f < F_DIM; ++f) dst[f] = f2bf(acc[f]);
}

// ---------- fused GEMM (M=65536, K=544, N=512) + tanh + dot(v_w) -> score[M] ----------
__launch_bounds__(256, 2)
__global__ void gemm_score(const float* __restrict__ values,
                           const unsigned short* __restrict__ Bt,
                           const unsigned short* __restrict__ convb,
                           const float* __restrict__ pq,
                           const float* __restrict__ vw,
                           float* __restrict__ score) {
    __shared__ __align__(16) short sA[64 * 40];    // 64 rows x 32 k, pad to 40
    __shared__ __align__(16) short sB[512 * 40];   // 512 a-rows x 32 k, pad to 40
    __shared__ float sPQ[512];
    __shared__ float sVW[512];
    __shared__ float sSc[64];                      // cross-wave score partials
    int tid = threadIdx.x;
    int m0 = blockIdx.x * 64;
    int b = m0 >> 10;
    for (int j = tid; j < 512; j += 256) { sPQ[j] = pq[b * 512 + j]; sVW[j] = vw[j]; }
    int w = tid >> 6, lane = tid & 63, q = lane >> 4, l15 = lane & 15;
    int wm = w & 1, wn = w >> 1;      // wave: rows wm*32..+31, cols wn*256..+255
    f32x4 acc0[16], acc1[16];
    #pragma unroll
    for (int n = 0; n < 16; ++n) { acc0[n] = (f32x4)0.f; acc1[n] = (f32x4)0.f; }
    int arow = tid >> 2, aseg = tid & 3;
    for (int c = 0; c < NCHUNK; ++c) {
        __syncthreads();
        // stage A-tile: 64 rows x 32 k bf16
        if (c < 16) {
            const float* src = values + (size_t)(m0 + arow) * DV + c * 32 + aseg * 8;
            float4 x0 = *(const float4*)src;
            float4 x1 = *(const float4*)(src + 4);
            short8 pk;
            pk[0] = (short)f2bf(x0.x); pk[1] = (short)f2bf(x0.y);
            pk[2] = (short)f2bf(x0.z); pk[3] = (short)f2bf(x0.w);
            pk[4] = (short)f2bf(x1.x); pk[5] = (short)f2bf(x1.y);
            pk[6] = (short)f2bf(x1.z); pk[7] = (short)f2bf(x1.w);
            *(short8*)&sA[arow * 40 + aseg * 8] = pk;
        } else {
            short8 pk = *(const short8*)(const void*)(convb + (size_t)(m0 + arow) * F_DIM + aseg * 8);
            *(short8*)&sA[arow * 40 + aseg * 8] = pk;
        }
        // stage B-tile: 512 a-rows x 32 k bf16 (shared by all 4 waves)
        #pragma unroll
        for (int j = 0; j < 8; ++j) {
            int task = j * 256 + tid;
            int a = task >> 2, seg = task & 3;
            short8 pk = *(const short8*)(const void*)(Bt + (size_t)a * KEXT + c * 32 + seg * 8);
            *(short8*)&sB[a * 40 + seg * 8] = pk;
        }
        __syncthreads();
        short8 af0 = *(const short8*)&sA[(wm * 32 + l15) * 40 + q * 8];
        short8 af1 = *(const short8*)&sA[(wm * 32 + 16 + l15) * 40 + q * 8];
        #pragma unroll
        for (int n = 0; n < 16; ++n) {
            short8 bfr = *(const short8*)&sB[(wn * 256 + n * 16 + l15) * 40 + q * 8];
            acc0[n] = __builtin_amdgcn_mfma_f32_16x16x32_bf16(af0, bfr, acc0[n], 0, 0, 0);
            acc1[n] = __builtin_amdgcn_mfma_f32_16x16x32_bf16(af1, bfr, acc1[n], 0, 0, 0);
        }
    }
    // epilogue: score[m] = sum_a tanh(PV+PQ)·v_w  (v_b dropped: softmax shift-invariant)
    // Each wave covers half the N-columns -> cross-wave add via LDS.
    float prt[2][4];
    #pragma unroll
    for (int mb = 0; mb < 2; ++mb) {
        #pragma unroll
        for (int r = 0; r < 4; ++r) {
            float s = 0.f;
            #pragma unroll
            for (int n = 0; n < 16; ++n) {
                int col = wn * 256 + n * 16 + l15;
                float x = (mb ? acc1[n][r] : acc0[n][r]) + sPQ[col];
                s += tanh_fast(x) * sVW[col];
            }
            #pragma unroll
            for (int off = 1; off < 16; off <<= 1) s += __shfl_xor(s, off, 64);
            prt[mb][r] = s;
        }
    }
    if (wn == 0 && l15 == 0) {
        #pragma unroll
        for (int mb = 0; mb < 2; ++mb)
            #pragma unroll
            for (int r = 0; r < 4; ++r)
                sSc[wm * 32 + mb * 16 + q * 4 + r] = prt[mb][r];
    }
    __syncthreads();
    if (wn == 1 && l15 == 0) {
        #pragma unroll
        for (int mb = 0; mb < 2; ++mb)
            #pragma unroll
            for (int r = 0; r < 4; ++r) {
                int row = wm * 32 + mb * 16 + q * 4 + r;
                score[m0 + row] = sSc[row] + prt[mb][r];
            }
    }
}

// ---------- softmax + forward-attention recursion + state outputs ----------
__global__ void softmax_fwd(const float* __restrict__ score,
                            const float* __restrict__ alpha,
                            const float* __restrict__ cum,
                            float* __restrict__ out) {
    int b = blockIdx.x, t = threadIdx.x;   // 1024 threads
    __shared__ float sred[16];
    __shared__ float sbc;
    float sc = score[b * T + t];
    int wid = t >> 6, lane = t & 63;
    float m = sc;
    #pragma unroll
    for (int off = 32; off; off >>= 1) m = fmaxf(m, __shfl_xor(m, off, 64));
    if (lane == 0) sred[wid] = m;
    __syncthreads();
    if (t == 0) { float mm = sred[0]; for (int i = 1; i < 16; ++i) mm = fmaxf(mm, sred[i]); sbc = mm; }
    __syncthreads();
    float M = sbc;
    float e = __expf(sc - M);
    float s = e;
    #pragma unroll
    for (int off = 32; off; off >>= 1) s += __shfl_xor(s, off, 64);
    __syncthreads();
    if (lane == 0) sred[wid] = s;
    __syncthreads();
    if (t == 0) { float ss = 0.f; for (int i = 0; i < 16; ++i) ss += sred[i]; sbc = ss; }
    __syncthreads();
    float sn = e / sbc;
    float a_t = alpha[b * T + t];
    float a_p = (t > 0) ? alpha[b * T + t - 1] : 0.f;
    float ua = (0.5f * (a_t + a_p) + 1e-8f) * sn;
    float u = ua;
    #pragma unroll
    for (int off = 32; off; off >>= 1) u += __shfl_xor(u, off, 64);
    __syncthreads();
    if (lane == 0) sred[wid] = u;
    __syncthreads();
    if (t == 0) { float ss = 0.f; for (int i = 0; i < 16; ++i) ss += sred[i]; sbc = ss; }
    __syncthreads();
    float wgt = ua / sbc;
    float* attnw  = out + B * DV;
    float* ncum   = attnw + B * T;
    float* nold   = ncum + B * T;
    float* nalpha = nold + B * T;
    attnw[b * T + t]  = wgt;
    ncum[b * T + t]   = cum[b * T + t] + sn;
    nold[b * T + t]   = wgt;
    nalpha[b * T + t] = wgt;
    if (t < DV) out[b * DV + t] = 0.f;   // zero context region for atomics
}

// ---------- context = attn_weights @ values ----------
__global__ void context_kernel(const float* __restrict__ values, float* __restrict__ out) {
    const float* attnw = out + B * DV;
    int bid = blockIdx.x;                 // 1024 = 64 b x 2 d-half x 8 t-slice
    int b = bid >> 4, r = bid & 15, dh = r & 1, sl = r >> 1;
    int d = dh * 256 + threadIdx.x;
    float acc = 0.f;
    int tbase = sl * 128;
    #pragma unroll 4
    for (int tt = 0; tt < 128; ++tt) {
        int t = tbase + tt;
        acc += attnw[b * T + t] * values[(size_t)(b * T + t) * DV + d];
    }
    atomicAdd(&out[b * DV + d], acc);
}

extern "C" void kernel_launch(void* const* d_in, const int* in_sizes, int n_in,
                              void* d_out, int out_size, void* d_ws, size_t ws_size,
                              hipStream_t stream) {
    const float* query  = (const float*)d_in[0];
    const float* values = (const float*)d_in[1];
    const float* cum    = (const float*)d_in[2];
    const float* old_   = (const float*)d_in[3];
    const float* alpha  = (const float*)d_in[4];
    const float* Wq     = (const float*)d_in[5];
    const float* Wi     = (const float*)d_in[6];
    const float* vw     = (const float*)d_in[7];
    // d_in[8] = v_b : dropped (softmax shift-invariant)
    const float* lk     = (const float*)d_in[9];
    const float* Wl     = (const float*)d_in[10];
    float* out = (float*)d_out;
    char* ws = (char*)d_ws;
    float* ws_pq            = (float*)(ws);                    // 131072 B
    float* ws_score         = (float*)(ws + 131072);           // 262144 B
    unsigned short* ws_Bt   = (unsigned short*)(ws + 393216);  // 557056 B
    unsigned short* ws_conv = (unsigned short*)(ws + 1048576); // 4 MiB

    pq_kernel<<<512, 256, 0, stream>>>(query, Wq, ws_pq);
    bt_kernel<<<512, 256, 0, stream>>>(Wi, Wl, ws_Bt);
    conv_kernel<<<512, 128, 0, stream>>>(old_, cum, lk, ws_conv);
    gemm_score<<<1024, 256, 0, stream>>>(values, ws_Bt, ws_conv, ws_pq, vw, ws_score);
    softmax_fwd<<<64, 1024, 0, stream>>>(ws_score, alpha, cum, out);
    context_kernel<<<1024, 256, 0, stream>>>(values, out);
}

// Round 4
// 307.939 us; speedup vs baseline: 1.3323x; 1.0224x over previous
//
#include <hip/hip_runtime.h>
#include <hip/hip_bf16.h>
#include <cstdint>
#include <cstddef>

#define B 64
#define T 1024
#define DQ 1024
#define DV 512
#define A_DIM 512
#define F_DIM 32
#define KW 31
#define M_TOT (B*T)
#define KEXT 544      // DV + F_DIM
#define NCHUNK 17     // KEXT / 32

typedef __attribute__((ext_vector_type(8))) short short8;
typedef __attribute__((ext_vector_type(4))) float f32x4;
typedef __attribute__((ext_vector_type(16))) float f32x16;

static __device__ __forceinline__ unsigned short f2bf(float f) {
    unsigned int u = __builtin_bit_cast(unsigned int, f);
    u += 0x7fffu + ((u >> 16) & 1u);   // RNE
    return (unsigned short)(u >> 16);
}

static __device__ __forceinline__ float tanh_fast(float x) {
    float e = __expf(2.0f * x);
    return 1.0f - 2.0f * __builtin_amdgcn_rcpf(e + 1.0f);
}

// ---------- prep: processed_query [B, A] fp32 ; also zeroes score ----------
// grid 512 = 64 b x 8 a-chunks(64); 256 thr = 64 a_local x 4 k-slices(256)
__global__ void pq_kernel(const float* __restrict__ query, const float* __restrict__ Wq,
                          float* __restrict__ pq, float* __restrict__ score) {
    __shared__ float red[4][64];
    int gid = blockIdx.x * 256 + threadIdx.x;
    if (gid < M_TOT) score[gid] = 0.f;          // gemm accumulates atomically
    int b = blockIdx.x >> 3, a0 = (blockIdx.x & 7) * 64;
    int al = threadIdx.x & 63, ks = threadIdx.x >> 6;
    const float* qr = query + (size_t)b * DQ + ks * 256;
    const float* wc = Wq + (size_t)(ks * 256) * A_DIM + a0 + al;
    float acc = 0.f;
    #pragma unroll 8
    for (int k = 0; k < 256; ++k) acc += qr[k] * wc[(size_t)k * A_DIM];
    red[ks][al] = acc;
    __syncthreads();
    if (ks == 0) {
        float s = red[0][al] + red[1][al] + red[2][al] + red[3][al];
        pq[b * A_DIM + a0 + al] = s;
    }
}

// ---------- prep: B_ext^T  [A][KEXT] bf16 ----------
__global__ void bt_kernel(const float* __restrict__ Wi, const float* __restrict__ Wl,
                          unsigned short* __restrict__ Bt) {
    int a = blockIdx.x;   // 512 blocks
    for (int k = threadIdx.x; k < KEXT; k += 256) {
        float v = (k < DV) ? Wi[(size_t)k * A_DIM + a] : Wl[(size_t)(k - DV) * A_DIM + a];
        Bt[(size_t)a * KEXT + k] = f2bf(v);
    }
}

// ---------- prep: location conv  [M][F] bf16 ----------
__global__ void conv_kernel(const float* __restrict__ old_, const float* __restrict__ cum_,
                            const float* __restrict__ lk, unsigned short* __restrict__ convb) {
    __shared__ float sOld[158], sCum[158];
    __shared__ float sLK[KW * 2 * F_DIM];
    int b = blockIdx.x >> 3, t0 = (blockIdx.x & 7) * 128;
    int tid = threadIdx.x;   // 128 threads
    for (int j = tid; j < 158; j += 128) {
        int tt = t0 - 15 + j;
        bool ok = (tt >= 0 && tt < T);
        sOld[j] = ok ? old_[b * T + tt] : 0.f;
        sCum[j] = ok ? cum_[b * T + tt] : 0.f;
    }
    for (int j = tid; j < KW * 2 * F_DIM; j += 128) sLK[j] = lk[j];
    __syncthreads();
    float acc[F_DIM];
    #pragma unroll
    for (int f = 0; f < F_DIM; ++f) acc[f] = 0.f;
    for (int k = 0; k < KW; ++k) {
        float o = sOld[tid + k], c = sCum[tid + k];
        const float* lo = &sLK[(k * 2 + 0) * F_DIM];
        const float* lc = &sLK[(k * 2 + 1) * F_DIM];
        #pragma unroll
        for (int f = 0; f < F_DIM; ++f) acc[f] += o * lo[f] + c * lc[f];
    }
    unsigned short* dst = convb + (size_t)(b * T + t0 + tid) * F_DIM;
    #pragma unroll
    for (int f = 0; f < F_DIM; ++f) dst[f] = f2bf(acc[f]);
}

// ---------- fused GEMM (M=65536, K=544, N=512) + tanh + dot(v_w) -> score[M] ----------
// block = 128 rows x 256 cols; grid 1024 = 512 m-tiles x 2 col-halves
// 4 waves, each 64 rows x 128 cols = 2x4 tiles of 32x32 (mfma_32x32x16_bf16)
__launch_bounds__(256, 2)
__global__ void gemm_score(const float* __restrict__ values,
                           const unsigned short* __restrict__ Bt,
                           const unsigned short* __restrict__ convb,
                           const float* __restrict__ pq,
                           const float* __restrict__ vw,
                           float* __restrict__ score) {
    __shared__ __align__(16) short sA[128 * 40];   // 128 rows x 32 k, pad to 40
    __shared__ __align__(16) short sB[256 * 40];   // 256 a-rows x 32 k, pad to 40
    __shared__ float sPQ[256];
    __shared__ float sVW[256];
    int tid = threadIdx.x;
    int mt = blockIdx.x >> 1, ch = blockIdx.x & 1;
    int m0 = mt * 128, n0 = ch * 256;
    int b = m0 >> 10;
    for (int j = tid; j < 256; j += 256) {
        sPQ[j] = pq[b * A_DIM + n0 + j];
        sVW[j] = vw[n0 + j];
    }
    int w = tid >> 6, lane = tid & 63;
    int l31 = lane & 31, lh = lane >> 5;
    int wm = w & 1, wn = w >> 1;      // wave: rows wm*64..+63, cols wn*128..+127
    f32x16 acc[2][4];
    #pragma unroll
    for (int mi = 0; mi < 2; ++mi)
        #pragma unroll
        for (int ni = 0; ni < 4; ++ni) acc[mi][ni] = (f32x16)0.f;

    for (int c = 0; c < NCHUNK; ++c) {
        __syncthreads();
        // stage A-tile: 128 rows x 32 k bf16 (512 tasks / 256 thr)
        #pragma unroll
        for (int j = 0; j < 2; ++j) {
            int task = j * 256 + tid;
            int row = task >> 2, seg = task & 3;
            short8 pk;
            if (c < 16) {
                const float* src = values + (size_t)(m0 + row) * DV + c * 32 + seg * 8;
                float4 x0 = *(const float4*)src;
                float4 x1 = *(const float4*)(src + 4);
                pk[0] = (short)f2bf(x0.x); pk[1] = (short)f2bf(x0.y);
                pk[2] = (short)f2bf(x0.z); pk[3] = (short)f2bf(x0.w);
                pk[4] = (short)f2bf(x1.x); pk[5] = (short)f2bf(x1.y);
                pk[6] = (short)f2bf(x1.z); pk[7] = (short)f2bf(x1.w);
            } else {
                pk = *(const short8*)(const void*)(convb + (size_t)(m0 + row) * F_DIM + seg * 8);
            }
            *(short8*)&sA[row * 40 + seg * 8] = pk;
        }
        // stage B-tile: 256 a-rows x 32 k bf16 (1024 tasks / 256 thr)
        #pragma unroll
        for (int j = 0; j < 4; ++j) {
            int task = j * 256 + tid;
            int ar = task >> 2, seg = task & 3;
            short8 pk = *(const short8*)(const void*)(Bt + (size_t)(n0 + ar) * KEXT + c * 32 + seg * 8);
            *(short8*)&sB[ar * 40 + seg * 8] = pk;
        }
        __syncthreads();
        #pragma unroll
        for (int kk = 0; kk < 2; ++kk) {
            short8 af[2], bf[4];
            #pragma unroll
            for (int mi = 0; mi < 2; ++mi)
                af[mi] = *(const short8*)&sA[(wm * 64 + mi * 32 + l31) * 40 + kk * 16 + lh * 8];
            #pragma unroll
            for (int ni = 0; ni < 4; ++ni)
                bf[ni] = *(const short8*)&sB[(wn * 128 + ni * 32 + l31) * 40 + kk * 16 + lh * 8];
            #pragma unroll
            for (int mi = 0; mi < 2; ++mi)
                #pragma unroll
                for (int ni = 0; ni < 4; ++ni)
                    acc[mi][ni] = __builtin_amdgcn_mfma_f32_32x32x16_bf16(af[mi], bf[ni], acc[mi][ni], 0, 0, 0);
        }
    }
    // epilogue: partial score over this block's 256 cols -> global atomicAdd
    // C/D 32x32 layout: col = lane&31, row = (reg&3) + 8*(reg>>2) + 4*(lane>>5)
    #pragma unroll
    for (int mi = 0; mi < 2; ++mi) {
        #pragma unroll
        for (int r = 0; r < 16; ++r) {
            float s = 0.f;
            #pragma unroll
            for (int ni = 0; ni < 4; ++ni) {
                int bcol = wn * 128 + ni * 32 + l31;
                float x = acc[mi][ni][r] + sPQ[bcol];
                s += tanh_fast(x) * sVW[bcol];
            }
            #pragma unroll
            for (int off = 1; off < 32; off <<= 1) s += __shfl_xor(s, off, 64);
            if (l31 == 0) {
                int row = wm * 64 + mi * 32 + (r & 3) + 8 * (r >> 2) + 4 * lh;
                atomicAdd(&score[m0 + row], s);
            }
        }
    }
}

// ---------- softmax + forward-attention recursion + state outputs ----------
__global__ void softmax_fwd(const float* __restrict__ score,
                            const float* __restrict__ alpha,
                            const float* __restrict__ cum,
                            float* __restrict__ out) {
    int b = blockIdx.x, t = threadIdx.x;   // 1024 threads
    __shared__ float sred[16];
    __shared__ float sbc;
    float sc = score[b * T + t];
    int wid = t >> 6, lane = t & 63;
    float m = sc;
    #pragma unroll
    for (int off = 32; off; off >>= 1) m = fmaxf(m, __shfl_xor(m, off, 64));
    if (lane == 0) sred[wid] = m;
    __syncthreads();
    if (t == 0) { float mm = sred[0]; for (int i = 1; i < 16; ++i) mm = fmaxf(mm, sred[i]); sbc = mm; }
    __syncthreads();
    float M = sbc;
    float e = __expf(sc - M);
    float s = e;
    #pragma unroll
    for (int off = 32; off; off >>= 1) s += __shfl_xor(s, off, 64);
    __syncthreads();
    if (lane == 0) sred[wid] = s;
    __syncthreads();
    if (t == 0) { float ss = 0.f; for (int i = 0; i < 16; ++i) ss += sred[i]; sbc = ss; }
    __syncthreads();
    float sn = e / sbc;
    float a_t = alpha[b * T + t];
    float a_p = (t > 0) ? alpha[b * T + t - 1] : 0.f;
    float ua = (0.5f * (a_t + a_p) + 1e-8f) * sn;
    float u = ua;
    #pragma unroll
    for (int off = 32; off; off >>= 1) u += __shfl_xor(u, off, 64);
    __syncthreads();
    if (lane == 0) sred[wid] = u;
    __syncthreads();
    if (t == 0) { float ss = 0.f; for (int i = 0; i < 16; ++i) ss += sred[i]; sbc = ss; }
    __syncthreads();
    float wgt = ua / sbc;
    float* attnw  = out + B * DV;
    float* ncum   = attnw + B * T;
    float* nold   = ncum + B * T;
    float* nalpha = nold + B * T;
    attnw[b * T + t]  = wgt;
    ncum[b * T + t]   = cum[b * T + t] + sn;
    nold[b * T + t]   = wgt;
    nalpha[b * T + t] = wgt;
    if (t < DV) out[b * DV + t] = 0.f;   // zero context region for atomics
}

// ---------- context = attn_weights @ values ----------
__global__ void context_kernel(const float* __restrict__ values, float* __restrict__ out) {
    const float* attnw = out + B * DV;
    int bid = blockIdx.x;                 // 2048 = 64 b x 2 d-half x 16 t-slice
    int b = bid >> 5, r = bid & 31, dh = r & 1, sl = r >> 1;
    int d = dh * 256 + threadIdx.x;
    float acc = 0.f;
    int tbase = sl * 64;
    #pragma unroll 4
    for (int tt = 0; tt < 64; ++tt) {
        int t = tbase + tt;
        acc += attnw[b * T + t] * values[(size_t)(b * T + t) * DV + d];
    }
    atomicAdd(&out[b * DV + d], acc);
}

extern "C" void kernel_launch(void* const* d_in, const int* in_sizes, int n_in,
                              void* d_out, int out_size, void* d_ws, size_t ws_size,
                              hipStream_t stream) {
    const float* query  = (const float*)d_in[0];
    const float* values = (const float*)d_in[1];
    const float* cum    = (const float*)d_in[2];
    const float* old_   = (const float*)d_in[3];
    const float* alpha  = (const float*)d_in[4];
    const float* Wq     = (const float*)d_in[5];
    const float* Wi     = (const float*)d_in[6];
    const float* vw     = (const float*)d_in[7];
    // d_in[8] = v_b : dropped (softmax shift-invariant)
    const float* lk     = (const float*)d_in[9];
    const float* Wl     = (const float*)d_in[10];
    float* out = (float*)d_out;
    char* ws = (char*)d_ws;
    float* ws_pq            = (float*)(ws);                    // 131072 B
    float* ws_score         = (float*)(ws + 131072);           // 262144 B
    unsigned short* ws_Bt   = (unsigned short*)(ws + 393216);  // 557056 B
    unsigned short* ws_conv = (unsigned short*)(ws + 1048576); // 4 MiB

    pq_kernel<<<512, 256, 0, stream>>>(query, Wq, ws_pq, ws_score);
    bt_kernel<<<512, 256, 0, stream>>>(Wi, Wl, ws_Bt);
    conv_kernel<<<512, 128, 0, stream>>>(old_, cum, lk, ws_conv);
    gemm_score<<<1024, 256, 0, stream>>>(values, ws_Bt, ws_conv, ws_pq, vw, ws_score);
    softmax_fwd<<<64, 1024, 0, stream>>>(ws_score, alpha, cum, out);
    context_kernel<<<2048, 256, 0, stream>>>(values, out);
}